// Round 3
// baseline (939.418 us; speedup 1.0000x reference)
//
#include <hip/hip_runtime.h>
#include <hip/hip_cooperative_groups.h>

namespace cg = cooperative_groups;

// ---------------------------------------------------------------------------
// PEPS 4x5, D=4, P=2, depth-5 gate sweeps, 64-point gather.
// psi kept in COLUMN-major qubit order: qubit (i,j) at bit (19 - 4*j - i).
// Gate evolution fused into one cooperative kernel with grid syncs.
// ---------------------------------------------------------------------------

#define PAD(i) ((i) + (((i) >> 4) << 2))   // +4 floats per 16 -> LDS bank spread
#define PIDX(i,j,p,u,d,l,r) (((((((i)*5+(j))*2+(p))*4+(u))*4+(d))*4+(l))*4+(r))

// workspace float offsets
static constexpr int COL0  = 0;                    // [16][256]
static constexpr int COL1  = 4096;                 // [16][256][256]
static constexpr int COL2  = COL1 + 1048576;
static constexpr int COL3  = COL2 + 1048576;
static constexpr int COL4  = COL3 + 1048576;       // [16][256]
static constexpr int M01TO = COL4 + 4096;          // [R2=256][c01=256]
static constexpr int M34TO = M01TO + 65536;        // [L3=256][c34=256]
static constexpr int T12TO = M34TO + 65536;        // [L3=256][c01*16+c2]
static constexpr int PSIO  = T12TO + 1048576;      // [2^20]

// --------------------------- column tensors --------------------------------
// Middle cols (1,2,3): 128 blocks each, compile-time shifts, float4 path.
// Edge cols (0,4): one block each, generic scalar path.
__global__ __launch_bounds__(256) void k_build_cols(const float* __restrict__ peps,
                                                    float* __restrict__ ws) {
  __shared__ float p01[4096], p23[4096];
  int bid = blockIdx.x, t = threadIdx.x;
  if (bid < 384) {
    int col = 1 + (bid >> 7);
    int part = bid & 127;
    // stage 1: p01/p23 [p(2)][d2(2)][l12(4)][r12(4)]
#pragma unroll
    for (int k = 0; k < 16; ++k) {
      int e = k * 256 + t;
      int r12 = e & 15, l12 = (e >> 4) & 15, d2 = (e >> 8) & 3, p = e >> 10;
      int l1 = l12 >> 2, l2 = l12 & 3, r1 = r12 >> 2, r2 = r12 & 3;
      float s01 = 0.f, s23 = 0.f;
#pragma unroll
      for (int d = 0; d < 4; ++d) {
        s01 += peps[PIDX(0, col, (p >> 1), 0, d, l1, r1)] *
               peps[PIDX(1, col, (p & 1), d, d2, l2, r2)];
        s23 += peps[PIDX(2, col, (p >> 1), d2, d, l1, r1)] *
               peps[PIDX(3, col, (p & 1), d, 0, l2, r2)];
      }
      p01[e] = s01;
      p23[e] = s23;
    }
    __syncthreads();
    // stage 2: out[p(4)][l12(4)][l34(4)][r12(4)][r34(4)], float4 over r34
    const int coloffs[3] = {COL1, COL2, COL3};
    float* out = ws + coloffs[col - 1];
#pragma unroll
    for (int k = 0; k < 8; ++k) {
      int eq = part * 8192 + (k * 256 + t) * 4;
      int r34b = eq & 15;
      int r12 = (eq >> 4) & 15, l34 = (eq >> 8) & 15, l12 = (eq >> 12) & 15;
      int p = eq >> 16;
      int pa = p >> 2, pb = p & 3;
      float4 acc = {0.f, 0.f, 0.f, 0.f};
#pragma unroll
      for (int d2 = 0; d2 < 4; ++d2) {
        float a01 = p01[((((pa * 4 + d2) << 4) | l12) << 4) | r12];
        const float4 b4 =
            *(const float4*)&p23[((((pb * 4 + d2) << 4) | l34) << 4) | r34b];
        acc.x += a01 * b4.x;
        acc.y += a01 * b4.y;
        acc.z += a01 * b4.z;
        acc.w += a01 * b4.w;
      }
      *(float4*)&out[eq] = acc;
    }
  } else {
    // edge columns, generic scalar
    int col = (bid == 384) ? 0 : 4;
    const int lsh = (col == 0) ? 0 : 2;
    const int rsh = (col == 4) ? 0 : 2;
    const int ldim = 1 << lsh, rdim = 1 << rsh;
    const int LLB = 2 * lsh, RRB = 2 * rsh;
    const int LL = 1 << LLB, RR = 1 << RRB;
    int n12 = (LL * RR) << 4;
    for (int e = t; e < n12; e += 256) {
      int r12 = e & (RR - 1);
      int l12 = (e >> RRB) & (LL - 1);
      int d2 = (e >> (RRB + LLB)) & 3;
      int p = e >> (RRB + LLB + 2);
      int l1 = l12 >> lsh, l2 = l12 & (ldim - 1);
      int r1 = r12 >> rsh, r2 = r12 & (rdim - 1);
      float s01 = 0.f, s23 = 0.f;
      for (int d = 0; d < 4; ++d) {
        s01 += peps[PIDX(0, col, (p >> 1), 0, d, l1, r1)] *
               peps[PIDX(1, col, (p & 1), d, d2, l2, r2)];
        s23 += peps[PIDX(2, col, (p >> 1), d2, d, l1, r1)] *
               peps[PIDX(3, col, (p & 1), d, 0, l2, r2)];
      }
      p01[e] = s01;
      p23[e] = s23;
    }
    __syncthreads();
    const int LB = 2 * LLB, RB = 2 * RRB;
    int total = 16 << (LB + RB);  // 4096
    float* out = ws + ((col == 0) ? COL0 : COL4);
    for (int e = t; e < total; e += 256) {
      int r = e & ((1 << RB) - 1);
      int l = (e >> RB) & ((1 << LB) - 1);
      int p = e >> (RB + LB);
      int r34 = r & (RR - 1), r12 = r >> RRB;
      int l34 = l & (LL - 1), l12 = l >> LLB;
      int pa = p >> 2, pb = p & 3;
      float s = 0.f;
      for (int d2 = 0; d2 < 4; ++d2) {
        s += p01[((((pa * 4 + d2) << LLB) | l12) << RRB) | r12] *
             p23[((((pb * 4 + d2) << LLB) | l34) << RRB) | r34];
      }
      out[e] = s;
    }
  }
}

// ------------------- M01T / M34T (edge-pair contractions) ------------------
__global__ __launch_bounds__(256) void k_small(const float* __restrict__ ws,
                                               float* __restrict__ m01t,
                                               float* __restrict__ m34t) {
  __shared__ float c3buf[4160], c4buf[4160];
  int t = threadIdx.x;
  int sub = blockIdx.x & 63;
  if (blockIdx.x < 64) {
    const float* col0 = ws + COL0;
    const float* col1 = ws + COL1;
    int c0 = sub >> 2;
    int c1b = (sub & 3) << 2;
    float a0 = 0.f, a1 = 0.f, a2 = 0.f, a3 = 0.f;
    for (int R1 = 0; R1 < 256; ++R1) {
      float a = col0[c0 * 256 + R1];
      a0 += a * col1[((c1b + 0) * 256 + R1) * 256 + t];
      a1 += a * col1[((c1b + 1) * 256 + R1) * 256 + t];
      a2 += a * col1[((c1b + 2) * 256 + R1) * 256 + t];
      a3 += a * col1[((c1b + 3) * 256 + R1) * 256 + t];
    }
    float4 v = {a0, a1, a2, a3};
    *(float4*)(m01t + t * 256 + c0 * 16 + c1b) = v;
  } else {
    const float* col3 = ws + COL3;
    const float* col4 = ws + COL4;
    for (int e = t; e < 4096; e += 256)
      c4buf[(e >> 8) * 260 + (e & 255)] = col4[e];
    for (int q = 0; q < 4; ++q) {
      int L3 = sub * 4 + q;
      __syncthreads();
      for (int e = t; e < 4096; e += 256)
        c3buf[(e >> 8) * 260 + (e & 255)] = col3[(e >> 8) * 65536 + L3 * 256 + (e & 255)];
      __syncthreads();
      int c3 = t >> 4, c4 = t & 15;
      float acc = 0.f;
      for (int B = 0; B < 256; ++B)
        acc += c3buf[c3 * 260 + B] * c4buf[c4 * 260 + B];
      m34t[L3 * 256 + t] = acc;
    }
  }
}

// ---------------- T012 = M01 x Col2 (stored [L3][P012]) --------------------
__global__ __launch_bounds__(256) void k_t012(const float* __restrict__ m01t,
                                              const float* __restrict__ col2,
                                              float* __restrict__ t012t) {
  int t = threadIdx.x;
  int c2 = blockIdx.x & 15, tg = blockIdx.x >> 4;
  float acc[16] = {};
  for (int R2 = 0; R2 < 256; ++R2) {
    float bv = col2[c2 * 65536 + R2 * 256 + t];
#pragma unroll
    for (int i = 0; i < 16; ++i)
      acc[i] += m01t[R2 * 256 + tg * 16 + i] * bv;
  }
#pragma unroll
  for (int i = 0; i < 16; ++i)
    t012t[t * 4096 + (tg * 16 + i) * 16 + c2] = acc[i];
}

// ---------------- psi = T012 x M34T  (psi[P012*256 + c34]) -----------------
__global__ __launch_bounds__(256) void k_psi0(const float* __restrict__ t012t,
                                              const float* __restrict__ m34t,
                                              float* __restrict__ psi) {
  int t = threadIdx.x;
  int tg = blockIdx.x;
  float acc[16] = {};
  for (int L3 = 0; L3 < 256; ++L3) {
    float bv = m34t[L3 * 256 + t];
#pragma unroll
    for (int i = 0; i < 16; ++i)
      acc[i] += t012t[L3 * 4096 + tg * 16 + i] * bv;
  }
#pragma unroll
  for (int i = 0; i < 16; ++i) psi[(tg * 16 + i) * 256 + t] = acc[i];
}

// ---------------- register-level 2-qubit gate ------------------------------
template <int NB, int HI, int LO>
__device__ __forceinline__ void gate2(float* x, const float* __restrict__ g) {
  constexpr int H = 1 << HI, L = 1 << LO, N = 1 << NB;
#pragma unroll
  for (int o = 0; o < N; ++o) {
    if (o & (H | L)) continue;
    float v0 = x[o], v1 = x[o + L], v2 = x[o + H], v3 = x[o + H + L];
    x[o]         = g[0]  * v0 + g[1]  * v1 + g[2]  * v2 + g[3]  * v3;
    x[o + L]     = g[4]  * v0 + g[5]  * v1 + g[6]  * v2 + g[7]  * v3;
    x[o + H]     = g[8]  * v0 + g[9]  * v1 + g[10] * v2 + g[11] * v3;
    x[o + H + L] = g[12] * v0 + g[13] * v1 + g[14] * v2 + g[15] * v3;
  }
}

// H row transform: 5-bit group (bit4 = leftmost column), bonds j: (4-j,3-j)
template <int S4, int S3, int S2, int S1, int S0>
__device__ __forceinline__ void hxf(float* s, const float* __restrict__ g, int b) {
  float x[32];
#pragma unroll
  for (int m = 0; m < 32; ++m) {
    int off = ((m >> 4) & 1) * S4 + ((m >> 3) & 1) * S3 + ((m >> 2) & 1) * S2 +
              ((m >> 1) & 1) * S1 + (m & 1) * S0;
    x[m] = s[PAD(b + off)];
  }
  gate2<5, 4, 3>(x, g);
  gate2<5, 3, 2>(x, g);
  gate2<5, 2, 1>(x, g);
  gate2<5, 1, 0>(x, g);
#pragma unroll
  for (int m = 0; m < 32; ++m) {
    int off = ((m >> 4) & 1) * S4 + ((m >> 3) & 1) * S3 + ((m >> 2) & 1) * S2 +
              ((m >> 1) & 1) * S1 + (m & 1) * S0;
    s[PAD(b + off)] = x[m];
  }
}

// V column transform: 4-bit nibble (bit3 = row 0), bonds i: (3-i,2-i)
template <int ST>
__device__ __forceinline__ void vxf(float* s, const float* __restrict__ g, int b) {
  float x[16];
#pragma unroll
  for (int m = 0; m < 16; ++m) x[m] = s[PAD(b + m * ST)];
  gate2<4, 3, 2>(x, g);
  gate2<4, 2, 1>(x, g);
  gate2<4, 1, 0>(x, g);
#pragma unroll
  for (int m = 0; m < 16; ++m) s[PAD(b + m * ST)] = x[m];
}

// --------------------------- fused evolution -------------------------------
__device__ __forceinline__ void phase_ha(float* __restrict__ psi, float* s,
                                         const float* g, int t, int o) {
  int base = ((o >> 6) & 3) * 262144 + ((o >> 4) & 3) * 16384 +
             ((o >> 2) & 3) * 1024 + (o & 3) * 64;
#pragma unroll
  for (int i = 0; i < 4; ++i) {
    int f = (i * 256 + t) * 4;
    int w = f & 63, c = (f >> 6) & 3, b = (f >> 8) & 3, a = (f >> 10) & 3;
    *(float4*)(s + PAD(f)) =
        *(const float4*)(psi + base + a * 65536 + b * 4096 + c * 256 + w);
  }
  __syncthreads();
  if (t < 128) {  // row 2: slab bits {11,9,7,5,1}
    int b2 = ((t >> 6) & 1) * 1024 + ((t >> 5) & 1) * 256 + ((t >> 4) & 1) * 64 +
             ((t >> 3) & 1) * 16 + ((t >> 2) & 1) * 8 + ((t >> 1) & 1) * 4 + (t & 1);
    hxf<2048, 512, 128, 32, 2>(s, g, b2);
  }
  __syncthreads();
  if (t < 128) {  // row 3: slab bits {10,8,6,4,0}
    int b3 = ((t >> 6) & 1) * 2048 + ((t >> 5) & 1) * 512 + ((t >> 4) & 1) * 128 +
             ((t >> 3) & 1) * 32 + ((t & 7) << 1);
    hxf<1024, 256, 64, 16, 1>(s, g, b3);
  }
  __syncthreads();
#pragma unroll
  for (int i = 0; i < 4; ++i) {
    int f = (i * 256 + t) * 4;
    int w = f & 63, c = (f >> 6) & 3, b = (f >> 8) & 3, a = (f >> 10) & 3;
    *(float4*)(psi + base + a * 65536 + b * 4096 + c * 256 + w) =
        *(const float4*)(s + PAD(f));
  }
}

__device__ __forceinline__ void phase_hb(float* __restrict__ psi, float* s,
                                         const float* g, int t, int o) {
  int base = ((o >> 6) & 3) * 65536 + ((o >> 4) & 3) * 4096 +
             ((o >> 2) & 3) * 256 + (o & 3) * 16;
#pragma unroll
  for (int i = 0; i < 4; ++i) {
    int f = (i * 256 + t) * 4;
    int w = f & 15, d = (f >> 4) & 3, c = (f >> 6) & 3, b = (f >> 8) & 3,
        a = (f >> 10) & 3;
    *(float4*)(s + PAD(f)) = *(const float4*)(psi + base + a * 262144 +
                                              b * 16384 + c * 1024 + d * 64 + w);
  }
  __syncthreads();
  if (t < 128) {  // row 0: slab bits {11,9,7,5,3}
    int b0 = ((t >> 6) & 1) * 1024 + ((t >> 5) & 1) * 256 + ((t >> 4) & 1) * 64 +
             ((t >> 3) & 1) * 16 + ((t >> 2) & 1) * 4 + (t & 3);
    hxf<2048, 512, 128, 32, 8>(s, g, b0);
  }
  __syncthreads();
  if (t < 128) {  // row 1: slab bits {10,8,6,4,2}
    int b1 = ((t >> 6) & 1) * 2048 + ((t >> 5) & 1) * 512 + ((t >> 4) & 1) * 128 +
             ((t >> 3) & 1) * 32 + ((t >> 2) & 1) * 8 + (t & 3);
    hxf<1024, 256, 64, 16, 4>(s, g, b1);
  }
  __syncthreads();
#pragma unroll
  for (int i = 0; i < 4; ++i) {
    int f = (i * 256 + t) * 4;
    int w = f & 15, d = (f >> 4) & 3, c = (f >> 6) & 3, b = (f >> 8) & 3,
        a = (f >> 10) & 3;
    *(float4*)(psi + base + a * 262144 + b * 16384 + c * 1024 + d * 64 + w) =
        *(const float4*)(s + PAD(f));
  }
}

__device__ __forceinline__ void phase_va(float* __restrict__ psi, float* s,
                                         const float* g, int t, int o) {
  int base = o * 4096;
#pragma unroll
  for (int i = 0; i < 4; ++i) {
    int f = (i * 256 + t) * 4;
    *(float4*)(s + PAD(f)) = *(const float4*)(psi + base + f);
  }
  __syncthreads();
  vxf<1>(s, g, t * 16);                          // c4
  __syncthreads();
  vxf<16>(s, g, ((t >> 4) << 8) | (t & 15));     // c3
  __syncthreads();
  vxf<256>(s, g, t);                             // c2
  __syncthreads();
#pragma unroll
  for (int i = 0; i < 4; ++i) {
    int f = (i * 256 + t) * 4;
    *(float4*)(psi + base + f) = *(const float4*)(s + PAD(f));
  }
}

__device__ __forceinline__ void phase_vb(float* __restrict__ psi, float* s,
                                         const float* g, int t, int o) {
#pragma unroll
  for (int i = 0; i < 4; ++i) {
    int f = (i * 256 + t) * 4;
    int h = f >> 4, w = f & 15;
    *(float4*)(s + PAD(f)) = *(const float4*)(psi + h * 4096 + o * 16 + w);
  }
  __syncthreads();
  vxf<256>(s, g, t);                             // c0 (slab bits 11..8)
  __syncthreads();
  vxf<16>(s, g, ((t >> 4) << 8) | (t & 15));     // c1 (slab bits 7..4)
  __syncthreads();
#pragma unroll
  for (int i = 0; i < 4; ++i) {
    int f = (i * 256 + t) * 4;
    int h = f >> 4, w = f & 15;
    *(float4*)(psi + h * 4096 + o * 16 + w) = *(const float4*)(s + PAD(f));
  }
}

__global__ __launch_bounds__(256) void k_evolve(float* __restrict__ psi,
                                                const float* __restrict__ gate,
                                                const int* __restrict__ x,
                                                float* __restrict__ out) {
  __shared__ float s[5120];
  cg::grid_group grid = cg::this_grid();
  float g[16];
#pragma unroll
  for (int i = 0; i < 16; ++i) g[i] = gate[i];
  int t = threadIdx.x;
  int o = blockIdx.x;
  for (int it = 0; it < 5; ++it) {
    phase_ha(psi, s, g, t, o);
    grid.sync();
    phase_hb(psi, s, g, t, o);
    grid.sync();
    phase_va(psi, s, g, t, o);
    grid.sync();
    phase_vb(psi, s, g, t, o);
    grid.sync();
  }
  if (blockIdx.x == 0 && t < 64) {
    int idx = 0;
#pragma unroll
    for (int q = 0; q < 20; ++q) {
      int i = q / 5, j = q % 5;
      idx |= x[t * 20 + q] << (19 - 4 * j - i);
    }
    out[t] = psi[idx];
  }
}

// ---------------------------------------------------------------------------
extern "C" void kernel_launch(void* const* d_in, const int* in_sizes, int n_in,
                              void* d_out, int out_size, void* d_ws, size_t ws_size,
                              hipStream_t stream) {
  const int* x = (const int*)d_in[0];
  const float* peps = (const float*)d_in[1];
  const float* gate = (const float*)d_in[2];
  float* ws = (float*)d_ws;
  float* psi = ws + PSIO;
  float* out = (float*)d_out;

  k_build_cols<<<386, 256, 0, stream>>>(peps, ws);
  k_small<<<128, 256, 0, stream>>>(ws, ws + M01TO, ws + M34TO);
  k_t012<<<256, 256, 0, stream>>>(ws + M01TO, ws + COL2, ws + T12TO);
  k_psi0<<<256, 256, 0, stream>>>(ws + T12TO, ws + M34TO, psi);

  void* args[] = {(void*)&psi, (void*)&gate, (void*)&x, (void*)&out};
  hipLaunchCooperativeKernel((void*)k_evolve, dim3(256), dim3(256), args, 0,
                             stream);
}

// Round 4
// 307.886 us; speedup vs baseline: 3.0512x; 3.0512x over previous
//
#include <hip/hip_runtime.h>

// ---------------------------------------------------------------------------
// PEPS 4x5, D=4, P=2, depth-5 gate sweeps, 64-point gather.
// psi kept in COLUMN-major qubit order: qubit (i,j) at bit (19 - 4*j - i).
// Multi-kernel structure (grid.sync measured ~25-30us/sync on gfx950 — dead).
// ---------------------------------------------------------------------------

#define PAD(i) ((i) + (((i) >> 4) << 2))   // +4 floats per 16 -> LDS bank spread
#define PIDX(i,j,p,u,d,l,r) (((((((i)*5+(j))*2+(p))*4+(u))*4+(d))*4+(l))*4+(r))

// workspace float offsets
static constexpr int COL0  = 0;                    // [16][256]
static constexpr int COL1  = 4096;                 // [16][256][256]
static constexpr int COL2  = COL1 + 1048576;
static constexpr int COL3  = COL2 + 1048576;
static constexpr int COL4  = COL3 + 1048576;       // [16][256]
static constexpr int M01TO = COL4 + 4096;          // [R2=256][c01=256]
static constexpr int M34TO = M01TO + 65536;        // [L3=256][c34=256]
static constexpr int T12TO = M34TO + 65536;        // [L3=256][c01*16+c2]
static constexpr int PSIO  = T12TO + 1048576;      // [2^20]

// --------------------------- column tensors --------------------------------
// Middle cols (1,2,3): 128 blocks each, compile-time shifts, float4 path.
// Edge cols (0,4): one block each, generic scalar path.
__global__ __launch_bounds__(256) void k_build_cols(const float* __restrict__ peps,
                                                    float* __restrict__ ws) {
  __shared__ float p01[4096], p23[4096];
  int bid = blockIdx.x, t = threadIdx.x;
  if (bid < 384) {
    int col = 1 + (bid >> 7);
    int part = bid & 127;
#pragma unroll
    for (int k = 0; k < 16; ++k) {
      int e = k * 256 + t;
      int r12 = e & 15, l12 = (e >> 4) & 15, d2 = (e >> 8) & 3, p = e >> 10;
      int l1 = l12 >> 2, l2 = l12 & 3, r1 = r12 >> 2, r2 = r12 & 3;
      float s01 = 0.f, s23 = 0.f;
#pragma unroll
      for (int d = 0; d < 4; ++d) {
        s01 += peps[PIDX(0, col, (p >> 1), 0, d, l1, r1)] *
               peps[PIDX(1, col, (p & 1), d, d2, l2, r2)];
        s23 += peps[PIDX(2, col, (p >> 1), d2, d, l1, r1)] *
               peps[PIDX(3, col, (p & 1), d, 0, l2, r2)];
      }
      p01[e] = s01;
      p23[e] = s23;
    }
    __syncthreads();
    const int coloffs[3] = {COL1, COL2, COL3};
    float* out = ws + coloffs[col - 1];
#pragma unroll
    for (int k = 0; k < 8; ++k) {
      int eq = part * 8192 + (k * 256 + t) * 4;
      int r34b = eq & 15;
      int r12 = (eq >> 4) & 15, l34 = (eq >> 8) & 15, l12 = (eq >> 12) & 15;
      int p = eq >> 16;
      int pa = p >> 2, pb = p & 3;
      float4 acc = {0.f, 0.f, 0.f, 0.f};
#pragma unroll
      for (int d2 = 0; d2 < 4; ++d2) {
        float a01 = p01[((((pa * 4 + d2) << 4) | l12) << 4) | r12];
        const float4 b4 =
            *(const float4*)&p23[((((pb * 4 + d2) << 4) | l34) << 4) | r34b];
        acc.x += a01 * b4.x;
        acc.y += a01 * b4.y;
        acc.z += a01 * b4.z;
        acc.w += a01 * b4.w;
      }
      *(float4*)&out[eq] = acc;
    }
  } else {
    int col = (bid == 384) ? 0 : 4;
    const int lsh = (col == 0) ? 0 : 2;
    const int rsh = (col == 4) ? 0 : 2;
    const int ldim = 1 << lsh, rdim = 1 << rsh;
    const int LLB = 2 * lsh, RRB = 2 * rsh;
    const int LL = 1 << LLB, RR = 1 << RRB;
    int n12 = (LL * RR) << 4;
    for (int e = t; e < n12; e += 256) {
      int r12 = e & (RR - 1);
      int l12 = (e >> RRB) & (LL - 1);
      int d2 = (e >> (RRB + LLB)) & 3;
      int p = e >> (RRB + LLB + 2);
      int l1 = l12 >> lsh, l2 = l12 & (ldim - 1);
      int r1 = r12 >> rsh, r2 = r12 & (rdim - 1);
      float s01 = 0.f, s23 = 0.f;
      for (int d = 0; d < 4; ++d) {
        s01 += peps[PIDX(0, col, (p >> 1), 0, d, l1, r1)] *
               peps[PIDX(1, col, (p & 1), d, d2, l2, r2)];
        s23 += peps[PIDX(2, col, (p >> 1), d2, d, l1, r1)] *
               peps[PIDX(3, col, (p & 1), d, 0, l2, r2)];
      }
      p01[e] = s01;
      p23[e] = s23;
    }
    __syncthreads();
    const int LB = 2 * LLB, RB = 2 * RRB;
    int total = 16 << (LB + RB);  // 4096
    float* out = ws + ((col == 0) ? COL0 : COL4);
    for (int e = t; e < total; e += 256) {
      int r = e & ((1 << RB) - 1);
      int l = (e >> RB) & ((1 << LB) - 1);
      int p = e >> (RB + LB);
      int r34 = r & (RR - 1), r12 = r >> RRB;
      int l34 = l & (LL - 1), l12 = l >> LLB;
      int pa = p >> 2, pb = p & 3;
      float s = 0.f;
      for (int d2 = 0; d2 < 4; ++d2) {
        s += p01[((((pa * 4 + d2) << LLB) | l12) << RRB) | r12] *
             p23[((((pb * 4 + d2) << LLB) | l34) << RRB) | r34];
      }
      out[e] = s;
    }
  }
}

// ------------------- M01T / M34T (edge-pair contractions) ------------------
// 384 blocks: 0..127 -> M01 (c0 x c1-pair), 128..383 -> M34 (one L3 each)
__global__ __launch_bounds__(256) void k_small(const float* __restrict__ ws,
                                               float* __restrict__ m01t,
                                               float* __restrict__ m34t) {
  __shared__ float c3buf[4112], c4buf[4112];
  int t = threadIdx.x;
  if (blockIdx.x < 128) {
    int sub = blockIdx.x;
    const float* col0 = ws + COL0;
    const float* col1 = ws + COL1;
    int c0 = sub >> 3;
    int c1b = (sub & 7) << 1;
    float a0 = 0.f, a1 = 0.f;
    for (int R1 = 0; R1 < 256; ++R1) {
      float a = col0[c0 * 256 + R1];  // uniform -> s_load
      a0 += a * col1[((c1b + 0) * 256 + R1) * 256 + t];
      a1 += a * col1[((c1b + 1) * 256 + R1) * 256 + t];
    }
    float2 v = {a0, a1};
    *(float2*)(m01t + t * 256 + c0 * 16 + c1b) = v;
  } else {
    int L3 = blockIdx.x - 128;  // 0..255
    const float* col3 = ws + COL3;
    const float* col4 = ws + COL4;
    for (int e = t; e < 4096; e += 256) {
      c4buf[(e >> 8) * 257 + (e & 255)] = col4[e];
      c3buf[(e >> 8) * 257 + (e & 255)] =
          col3[(e >> 8) * 65536 + L3 * 256 + (e & 255)];
    }
    __syncthreads();
    int c3 = t >> 4, c4 = t & 15;
    float acc = 0.f;
    for (int B = 0; B < 256; ++B)
      acc += c3buf[c3 * 257 + B] * c4buf[c4 * 257 + B];
    m34t[L3 * 256 + t] = acc;
  }
}

// ---------------- T012 = M01 x Col2 (stored [L3][P012]) --------------------
__global__ __launch_bounds__(256) void k_t012(const float* __restrict__ m01t,
                                              const float* __restrict__ col2,
                                              float* __restrict__ t012t) {
  int t = threadIdx.x;
  int c2 = blockIdx.x & 15, tg = blockIdx.x >> 4;
  float acc[16] = {};
  for (int R2 = 0; R2 < 256; ++R2) {
    float bv = col2[c2 * 65536 + R2 * 256 + t];
#pragma unroll
    for (int i = 0; i < 16; ++i)
      acc[i] += m01t[R2 * 256 + tg * 16 + i] * bv;  // uniform -> s_load_dwordx4
  }
#pragma unroll
  for (int i = 0; i < 16; ++i)
    t012t[t * 4096 + (tg * 16 + i) * 16 + c2] = acc[i];
}

// ---------------- psi = T012 x M34T  (psi[P012*256 + c34]) -----------------
__global__ __launch_bounds__(256) void k_psi0(const float* __restrict__ t012t,
                                              const float* __restrict__ m34t,
                                              float* __restrict__ psi) {
  int t = threadIdx.x;
  int tg = blockIdx.x;
  float acc[16] = {};
  for (int L3 = 0; L3 < 256; ++L3) {
    float bv = m34t[L3 * 256 + t];
#pragma unroll
    for (int i = 0; i < 16; ++i)
      acc[i] += t012t[L3 * 4096 + tg * 16 + i] * bv;
  }
#pragma unroll
  for (int i = 0; i < 16; ++i) psi[(tg * 16 + i) * 256 + t] = acc[i];
}

// ---------------- register-level 2-qubit gate ------------------------------
template <int NB, int HI, int LO>
__device__ __forceinline__ void gate2(float* x, const float* __restrict__ g) {
  constexpr int H = 1 << HI, L = 1 << LO, N = 1 << NB;
#pragma unroll
  for (int o = 0; o < N; ++o) {
    if (o & (H | L)) continue;
    float v0 = x[o], v1 = x[o + L], v2 = x[o + H], v3 = x[o + H + L];
    x[o]         = g[0]  * v0 + g[1]  * v1 + g[2]  * v2 + g[3]  * v3;
    x[o + L]     = g[4]  * v0 + g[5]  * v1 + g[6]  * v2 + g[7]  * v3;
    x[o + H]     = g[8]  * v0 + g[9]  * v1 + g[10] * v2 + g[11] * v3;
    x[o + H + L] = g[12] * v0 + g[13] * v1 + g[14] * v2 + g[15] * v3;
  }
}

// H row transform: 5-bit group (bit4 = leftmost column), bonds j: (4-j,3-j)
template <int S4, int S3, int S2, int S1, int S0>
__device__ __forceinline__ void hxf(float* s, const float* __restrict__ g, int b) {
  float x[32];
#pragma unroll
  for (int m = 0; m < 32; ++m) {
    int off = ((m >> 4) & 1) * S4 + ((m >> 3) & 1) * S3 + ((m >> 2) & 1) * S2 +
              ((m >> 1) & 1) * S1 + (m & 1) * S0;
    x[m] = s[PAD(b + off)];
  }
  gate2<5, 4, 3>(x, g);
  gate2<5, 3, 2>(x, g);
  gate2<5, 2, 1>(x, g);
  gate2<5, 1, 0>(x, g);
#pragma unroll
  for (int m = 0; m < 32; ++m) {
    int off = ((m >> 4) & 1) * S4 + ((m >> 3) & 1) * S3 + ((m >> 2) & 1) * S2 +
              ((m >> 1) & 1) * S1 + (m & 1) * S0;
    s[PAD(b + off)] = x[m];
  }
}

// V column transform: 4-bit nibble (bit3 = row 0), bonds i: (3-i,2-i)
template <int ST>
__device__ __forceinline__ void vxf(float* s, const float* __restrict__ g, int b) {
  float x[16];
#pragma unroll
  for (int m = 0; m < 16; ++m) x[m] = s[PAD(b + m * ST)];
  gate2<4, 3, 2>(x, g);
  gate2<4, 2, 1>(x, g);
  gate2<4, 1, 0>(x, g);
#pragma unroll
  for (int m = 0; m < 16; ++m) s[PAD(b + m * ST)] = x[m];
}

// H phase A: rows 2,3 ; slab bits {17,16,13,12,9,8,5..0}
__global__ __launch_bounds__(128) void k_ha(float* __restrict__ psi,
                                            const float* __restrict__ gate) {
  __shared__ float s[5120];
  float g[16];
#pragma unroll
  for (int i = 0; i < 16; ++i) g[i] = gate[i];
  int t = threadIdx.x;  // 128
  int o = blockIdx.x;   // outer bits {19,18,15,14,11,10,7,6}
  int base = ((o >> 6) & 3) * 262144 + ((o >> 4) & 3) * 16384 +
             ((o >> 2) & 3) * 1024 + (o & 3) * 64;
#pragma unroll
  for (int i = 0; i < 8; ++i) {
    int f = (i * 128 + t) * 4;
    int w = f & 63, c = (f >> 6) & 3, b = (f >> 8) & 3, a = (f >> 10) & 3;
    *(float4*)(s + PAD(f)) =
        *(const float4*)(psi + base + a * 65536 + b * 4096 + c * 256 + w);
  }
  __syncthreads();
  {  // row 2: slab bits {11,9,7,5,1}
    int b2 = ((t >> 6) & 1) * 1024 + ((t >> 5) & 1) * 256 + ((t >> 4) & 1) * 64 +
             ((t >> 3) & 1) * 16 + ((t >> 2) & 1) * 8 + ((t >> 1) & 1) * 4 + (t & 1);
    hxf<2048, 512, 128, 32, 2>(s, g, b2);
  }
  __syncthreads();
  {  // row 3: slab bits {10,8,6,4,0}
    int b3 = ((t >> 6) & 1) * 2048 + ((t >> 5) & 1) * 512 + ((t >> 4) & 1) * 128 +
             ((t >> 3) & 1) * 32 + ((t & 7) << 1);
    hxf<1024, 256, 64, 16, 1>(s, g, b3);
  }
  __syncthreads();
#pragma unroll
  for (int i = 0; i < 8; ++i) {
    int f = (i * 128 + t) * 4;
    int w = f & 63, c = (f >> 6) & 3, b = (f >> 8) & 3, a = (f >> 10) & 3;
    *(float4*)(psi + base + a * 65536 + b * 4096 + c * 256 + w) =
        *(const float4*)(s + PAD(f));
  }
}

// H phase B: rows 0,1 + V col 4 ; slab bits {19,18,15,14,11,10,7,6,3..0}
__global__ __launch_bounds__(128) void k_hb(float* __restrict__ psi,
                                            const float* __restrict__ gate) {
  __shared__ float s[5120];
  float g[16];
#pragma unroll
  for (int i = 0; i < 16; ++i) g[i] = gate[i];
  int t = threadIdx.x;  // 128
  int o = blockIdx.x;   // outer bits {17,16,13,12,9,8,5,4}
  int base = ((o >> 6) & 3) * 65536 + ((o >> 4) & 3) * 4096 +
             ((o >> 2) & 3) * 256 + (o & 3) * 16;
#pragma unroll
  for (int i = 0; i < 8; ++i) {
    int f = (i * 128 + t) * 4;
    int w = f & 15, d = (f >> 4) & 3, c = (f >> 6) & 3, b = (f >> 8) & 3,
        a = (f >> 10) & 3;
    *(float4*)(s + PAD(f)) = *(const float4*)(psi + base + a * 262144 +
                                              b * 16384 + c * 1024 + d * 64 + w);
  }
  __syncthreads();
  {  // row 0: slab bits {11,9,7,5,3}
    int b0 = ((t >> 6) & 1) * 1024 + ((t >> 5) & 1) * 256 + ((t >> 4) & 1) * 64 +
             ((t >> 3) & 1) * 16 + ((t >> 2) & 1) * 4 + (t & 3);
    hxf<2048, 512, 128, 32, 8>(s, g, b0);
  }
  __syncthreads();
  {  // row 1: slab bits {10,8,6,4,2}
    int b1 = ((t >> 6) & 1) * 2048 + ((t >> 5) & 1) * 512 + ((t >> 4) & 1) * 128 +
             ((t >> 3) & 1) * 32 + ((t >> 2) & 1) * 8 + (t & 3);
    hxf<1024, 256, 64, 16, 4>(s, g, b1);
  }
  __syncthreads();
  // V col 4 (slab bits 3..0): all H for col-4 qubits is complete here.
  vxf<1>(s, g, (2 * t) * 16);
  vxf<1>(s, g, (2 * t + 1) * 16);
  __syncthreads();
#pragma unroll
  for (int i = 0; i < 8; ++i) {
    int f = (i * 128 + t) * 4;
    int w = f & 15, d = (f >> 4) & 3, c = (f >> 6) & 3, b = (f >> 8) & 3,
        a = (f >> 10) & 3;
    *(float4*)(psi + base + a * 262144 + b * 16384 + c * 1024 + d * 64 + w) =
        *(const float4*)(s + PAD(f));
  }
}

// V phase A: cols c2,c3 (bits 11..4; slab bits 11..0)
__global__ __launch_bounds__(256) void k_va(float* __restrict__ psi,
                                            const float* __restrict__ gate) {
  __shared__ float s[5120];
  float g[16];
#pragma unroll
  for (int i = 0; i < 16; ++i) g[i] = gate[i];
  int t = threadIdx.x;
  int base = blockIdx.x * 4096;
#pragma unroll
  for (int i = 0; i < 4; ++i) {
    int f = (i * 256 + t) * 4;
    *(float4*)(s + PAD(f)) = *(const float4*)(psi + base + f);
  }
  __syncthreads();
  vxf<16>(s, g, ((t >> 4) << 8) | (t & 15));     // c3
  __syncthreads();
  vxf<256>(s, g, t);                             // c2
  __syncthreads();
#pragma unroll
  for (int i = 0; i < 4; ++i) {
    int f = (i * 256 + t) * 4;
    *(float4*)(psi + base + f) = *(const float4*)(s + PAD(f));
  }
}

// V phase B: cols c0,c1 (bits 19..12) ; slab bits {19..12, 3..0}
__global__ __launch_bounds__(256) void k_vb(float* __restrict__ psi,
                                            const float* __restrict__ gate) {
  __shared__ float s[5120];
  float g[16];
#pragma unroll
  for (int i = 0; i < 16; ++i) g[i] = gate[i];
  int t = threadIdx.x;
  int o = blockIdx.x;  // bits 11..4
#pragma unroll
  for (int i = 0; i < 4; ++i) {
    int f = (i * 256 + t) * 4;
    int h = f >> 4, w = f & 15;
    *(float4*)(s + PAD(f)) = *(const float4*)(psi + h * 4096 + o * 16 + w);
  }
  __syncthreads();
  vxf<256>(s, g, t);                             // c0 (slab bits 11..8)
  __syncthreads();
  vxf<16>(s, g, ((t >> 4) << 8) | (t & 15));     // c1 (slab bits 7..4)
  __syncthreads();
#pragma unroll
  for (int i = 0; i < 4; ++i) {
    int f = (i * 256 + t) * 4;
    int h = f >> 4, w = f & 15;
    *(float4*)(psi + h * 4096 + o * 16 + w) = *(const float4*)(s + PAD(f));
  }
}

// --------------------------- output gather ---------------------------------
__global__ __launch_bounds__(64) void k_gather(const int* __restrict__ x,
                                               const float* __restrict__ psi,
                                               float* __restrict__ out) {
  int b = threadIdx.x;
  int idx = 0;
#pragma unroll
  for (int q = 0; q < 20; ++q) {
    int i = q / 5, j = q % 5;
    idx |= x[b * 20 + q] << (19 - 4 * j - i);
  }
  out[b] = psi[idx];
}

// ---------------------------------------------------------------------------
extern "C" void kernel_launch(void* const* d_in, const int* in_sizes, int n_in,
                              void* d_out, int out_size, void* d_ws, size_t ws_size,
                              hipStream_t stream) {
  const int* x = (const int*)d_in[0];
  const float* peps = (const float*)d_in[1];
  const float* gate = (const float*)d_in[2];
  float* ws = (float*)d_ws;
  float* psi = ws + PSIO;

  k_build_cols<<<386, 256, 0, stream>>>(peps, ws);
  k_small<<<384, 256, 0, stream>>>(ws, ws + M01TO, ws + M34TO);
  k_t012<<<256, 256, 0, stream>>>(ws + M01TO, ws + COL2, ws + T12TO);
  k_psi0<<<256, 256, 0, stream>>>(ws + T12TO, ws + M34TO, psi);
  for (int it = 0; it < 5; ++it) {
    k_ha<<<256, 128, 0, stream>>>(psi, gate);
    k_hb<<<256, 128, 0, stream>>>(psi, gate);
    k_va<<<256, 256, 0, stream>>>(psi, gate);
    k_vb<<<256, 256, 0, stream>>>(psi, gate);
  }
  k_gather<<<1, 64, 0, stream>>>(x, psi, (float*)d_out);
}